// Round 3
// baseline (444.923 us; speedup 1.0000x reference)
//
#include <hip/hip_runtime.h>

// 3x3 median pool, stride 1, zero-pad 1, (8,32,512,512) fp32.
//
// Shfl-free rolling-register stencil. One wave owns a 32-row x 256-col strip.
// Lane i owns output cols x0..x0+3 and loads its OWN 6 input columns each row:
//   A = dwordx4 @ (x0-1)  -> cols x0-1 .. x0+2   (4B-aligned load)
//   B = dwordx2 @ (x0+3)  -> cols x0+3, x0+4
// 24 B/lane/row; the bytes overlapping neighbor lanes are L1 hits. This
// removes ALL cross-lane traffic (round-2 kernel burned 6 ds_bpermute +
// lgkmcnt waits per row on the sorted-column exchange) and the divergent
// halo load (which forced conservative vmcnt drains per row).
//
// All loop loads are UNCONDITIONAL (static vmcnt): image-edge lanes clamp
// the address and fix values with lane-constant cndmasks; bottom-strip
// overrun rows load a clamped valid row, then a wave-uniform branch zeroes
// the registers after the load.
//
// Ring depth 4 (static slots after 4x unroll): iter r issues the load of
// input row r+2, then computes output row r from rows r-1,r,r+1 -> one full
// row of VALU between a load and its first use, plus TLP.
//
// Occupancy: 8192 waves = 2048 blocks x 4 waves = exactly 32 waves/CU in one
// generation; __launch_bounds__(256,8) pins VGPR <= 64 so all are resident.
// Each block covers 4 vertically-adjacent strips -> 3 of its 5 boundary-row
// pairs are CU-local (L1).

typedef float f32x4 __attribute__((ext_vector_type(4)));
typedef float f32x2 __attribute__((ext_vector_type(2)));

#define S2(a, b) { float _t = fminf(a, b); b = fmaxf(a, b); a = _t; }

__device__ __forceinline__ float med3f(float a, float b, float c) {
    return fmaxf(fminf(a, b), fminf(fmaxf(a, b), c));
}
__device__ __forceinline__ float max3f(float a, float b, float c) {
    return fmaxf(fmaxf(a, b), c);
}
__device__ __forceinline__ float min3f(float a, float b, float c) {
    return fminf(fminf(a, b), c);
}

__global__ __launch_bounds__(256, 8) void median_pool3x3_kernel(
        const float* __restrict__ in, float* __restrict__ out) {
    constexpr int W = 512, H = 512;
    constexpr int RPW = 32;                // output rows per wave

    const int lane = threadIdx.x & 63;
    const int wib  = threadIdx.x >> 6;
    const int gw   = blockIdx.x * 4 + wib;

    // gw -> { img (256), half (2), strip (16) }; the 4 waves of a block are
    // 4 vertically-adjacent strips of the same (img, half).
    const int strip = gw & 15;
    const int half  = (gw >> 4) & 1;
    const int img   = gw >> 5;

    const int y0  = strip * RPW;
    const int x0w = half * 256;
    const int x0  = x0w + lane * 4;

    const float* __restrict__ base  = in  + (size_t)img * H * W;
    float* __restrict__       obase = out + (size_t)img * H * W;

    // Image-edge fixups (lane-constant). Interior wave edges read the
    // neighbor half's columns directly from memory (valid addresses).
    const bool fixL = (x0 == 0);           // needs col -1 (zero)
    const bool fixR = (x0 == W - 4);       // needs col 512 (zero)
    const int  offA = fixL ? 0        : (x0 - 1);   // 4 cols from here
    const int  offB = fixR ? (x0 + 2) : (x0 + 3);   // 2 cols from here

    // Unconditional 6-column row load + lane-constant value fixups.
    auto loadrow = [&](int y, f32x4& A, f32x2& B) {
        const float* row = base + (size_t)y * W;
        f32x4 a; __builtin_memcpy(&a, row + offA, 16);
        f32x2 b; __builtin_memcpy(&b, row + offB, 8);
        if (fixL) a = f32x4{0.0f, a.x, a.y, a.z};   // (0, c0, c1, c2)
        if (fixR) b = f32x2{b.y, 0.0f};             // (c511, 0)
        A = a; B = b;
    };

    // Median of the 3x3 window centered at col x0+j, rows y-1..y+1:
    // vertical 3-sort per column, then med3(max3(lo), med3(mi), min3(hi)).
    auto crow = [&](const f32x4& A0, const f32x2& B0,
                    const f32x4& A1, const f32x2& B1,
                    const f32x4& A2, const f32x2& B2, int y) {
        float lo[6], mi[6], hi[6];
        {
            const float c0[6] = {A0.x, A0.y, A0.z, A0.w, B0.x, B0.y};
            const float c1[6] = {A1.x, A1.y, A1.z, A1.w, B1.x, B1.y};
            const float c2[6] = {A2.x, A2.y, A2.z, A2.w, B2.x, B2.y};
            #pragma unroll
            for (int j = 0; j < 6; ++j) {
                float a = c0[j], b = c1[j], c = c2[j];
                S2(a, b); S2(b, c); S2(a, b);
                lo[j] = a; mi[j] = b; hi[j] = c;
            }
        }
        float o[4];
        #pragma unroll
        for (int j = 0; j < 4; ++j) {
            o[j] = med3f(max3f(lo[j], lo[j + 1], lo[j + 2]),
                         med3f(mi[j], mi[j + 1], mi[j + 2]),
                         min3f(hi[j], hi[j + 1], hi[j + 2]));
        }
        f32x4 ov = {o[0], o[1], o[2], o[3]};
        *(f32x4*)(obase + (size_t)y * W + x0) = ov;
    };

    // Ring: input row k (relative to y0, k = y - y0) lives in slot (k+1)&3.
    f32x4 ra[4];
    f32x2 rb[4];

    // ---- prologue: input rows y0-1, y0, y0+1 -> slots 0,1,2 ----
    if (y0 > 0) {                          // wave-uniform
        loadrow(y0 - 1, ra[0], rb[0]);
    } else {
        ra[0] = f32x4{0.0f, 0.0f, 0.0f, 0.0f};
        rb[0] = f32x2{0.0f, 0.0f};
    }
    loadrow(y0,     ra[1], rb[1]);
    loadrow(y0 + 1, ra[2], rb[2]);

    // ---- main loop: iter r loads input row r+2, computes output row r ----
    #pragma unroll 1
    for (int rbase = 0; rbase < RPW; rbase += 4) {
        #pragma unroll
        for (int q = 0; q < 4; ++q) {
            const int r  = rbase + q;
            const int yl = y0 + r + 2;                 // row to load
            const int sl = (r + 3) & 3;
            loadrow(yl < H ? yl : (H - 1), ra[sl], rb[sl]);  // unconditional
            if (yl >= H) {                             // wave-uniform zeroing
                ra[sl] = f32x4{0.0f, 0.0f, 0.0f, 0.0f};
                rb[sl] = f32x2{0.0f, 0.0f};
            }
            crow(ra[r & 3],       rb[r & 3],
                 ra[(r + 1) & 3], rb[(r + 1) & 3],
                 ra[(r + 2) & 3], rb[(r + 2) & 3],
                 y0 + r);
        }
    }
}

extern "C" void kernel_launch(void* const* d_in, const int* in_sizes, int n_in,
                              void* d_out, int out_size, void* d_ws, size_t ws_size,
                              hipStream_t stream) {
    const float* x = (const float*)d_in[0];
    float* out = (float*)d_out;

    // 256 planes x 2 halves x 16 strips = 8192 waves / 4 per block
    median_pool3x3_kernel<<<2048, 256, 0, stream>>>(x, out);
}